// Round 4
// baseline (4724.277 us; speedup 1.0000x reference)
//
#include <hip/hip_runtime.h>
#include <hip/hip_cooperative_groups.h>

// ConvGRU, fp16 MFMA implicit GEMM — PERSISTENT COOPERATIVE kernel.
// R4: the R2/R3 counters showed each cell dispatch at 36-48us vs ~3-5us of
// resource floor (MfmaUtil 15%, VALU 30%, Occ 19-28%): serialization-bound
// (32 dependent launches x {launch + DMA-drain + barrier convoy + tail}).
// Fix: ONE cooperative kernel runs the whole T-loop with grid.sync()
// between cell steps (grid.sync provides the cross-XCD release/acquire the
// kernel boundary used to provide). Geometry for guaranteed co-residency:
//   - tile 8 rows x 32 cols, 512 threads (8 waves), grid 512 = 2 WG/CU
//     (LDS 78.8KB <= 80KB; __launch_bounds__(512,4) caps VGPR at 128)
//   - 16 waves/CU, no dispatch tail, better halo ratio (gates 10x34 for
//     8x32 out vs 6x34 for 4x32)
//   - final NCHW output written inline at t=15 via LDS transpose (rh reused
//     as scratch) -> no final_out dispatch, no last h1 global write
//   - host falls back to 32 per-step dispatches of the same cell body if
//     the cooperative launch is rejected (correct either way).
// States fp16 NHWC padded planes [B][130][130][32], 1-px zero halo,
// ping-pong buffered. Stage tile 12x36 (2-px halo) via global_load_lds;
// clamped rows/cols land in the zero halo ring == SAME-pad value.

#define HH 128
#define PH 130
#define HW 16384
#define BB 8
#define TT 16

namespace cg = cooperative_groups;

typedef _Float16 f16x8 __attribute__((ext_vector_type(8)));
typedef float f32x4 __attribute__((ext_vector_type(4)));
typedef unsigned int u32x4 __attribute__((ext_vector_type(4)));

__device__ __forceinline__ unsigned short f2h(float x){
    return __builtin_bit_cast(unsigned short, (_Float16)x);
}
__device__ __forceinline__ float h2f(unsigned short u){
    return (float)__builtin_bit_cast(_Float16, u);
}
__device__ __forceinline__ f16x8 ld_frag(const unsigned short* p){
    u32x4 v = *(const u32x4*)p;
    return __builtin_bit_cast(f16x8, v);
}
__device__ __forceinline__ f16x8 lds_frag_w(const unsigned short* base, int spix, int q){
    u32x4 v = *(const u32x4*)(base + spix * 32 + q * 8);
    return __builtin_bit_cast(f16x8, v);
}
__device__ __forceinline__ float sigmoid_f(float a){ return 1.0f / (1.0f + __expf(-a)); }
__device__ __forceinline__ float tanh_f(float a){ float e2 = __expf(2.0f * a); return 1.0f - 2.0f / (e2 + 1.0f); }

// LDS block: 2 stage planes 12x36x32 fp16 + rh 10x34x32 fp16 + x 12x37 fp32
struct SmemT {
    unsigned short hs[2][13824];   // 55,296 B
    unsigned short rh[10880];      // 21,760 B (also out-transpose scratch)
    float xt[444];                 //  1,776 B   => 78,832 B total
};

// halo enumeration for 10x34 gates region: 84 px (rows 0,9 full; rows 1..8
// cols 0,33) as 6 16-px M-tiles; s>83 clamps (benign same-value dups).
__device__ __forceinline__ void halo_rc10(int s, int& gr, int& gc){
    s = s > 83 ? 83 : s;
    if (s < 34)      { gr = 0;            gc = s;      }
    else if (s < 68) { gr = 9;            gc = s - 34; }
    else if (s < 76) { gr = 1 + (s - 68); gc = 0;      }
    else             { gr = 1 + (s - 76); gc = 33;     }
}

// im2col x fragment for gates pixel (gr,gc); xt stride 37, origin R0-2,C0-2
__device__ __forceinline__ f16x8 x_im2col(const float* xt, int gr, int gc, int q){
    f16x8 v;
#pragma unroll
    for (int j = 0; j < 8; ++j) {
        int k = q * 8 + j;
        float f = 0.0f;
        if (k < 9) f = xt[(gr + k / 3) * 37 + gc + k % 3];
        v[j] = (_Float16)f;
    }
    return v;
}

// ---- async DMA staging: 12x36 tile = 432 px * 4 chunks = 1728 = 27*64 ----
__device__ __forceinline__ void stage_plane12(unsigned short* slot,
    const unsigned short* __restrict__ g, int b, int pr0, int pc0)
{
    const int wv = threadIdx.x >> 6, lane = threadIdx.x & 63;
    for (int k = wv; k < 27; k += 8) {
        int chunk = k * 64 + lane;
        int pix = chunk >> 2, part = chunk & 3;
        int r = pix / 36, c = pix - r * 36;
        int pr = pr0 + r; pr = pr < 0 ? 0 : (pr > 129 ? 129 : pr);
        int pc = pc0 + c; pc = pc < 0 ? 0 : (pc > 129 ? 129 : pc);
        const unsigned short* ga = g + ((long)((b * PH + pr) * PH + pc) * 32 + part * 8);
        __builtin_amdgcn_global_load_lds(
            (const __attribute__((address_space(1))) unsigned int*)ga,
            (__attribute__((address_space(3))) unsigned int*)(slot + k * 512),
            16, 0, 0);
    }
}

// ---- weight prep: [cout][cin_tot][9] fp32 -> [step][cout][32] fp16 ----
__global__ void prep_w(const float* __restrict__ w, unsigned short* __restrict__ wf,
                       int CO, int CIT, int NSTEP, int xmode)
{
    int idx = blockIdx.x * 256 + threadIdx.x;
    int total = NSTEP * CO * 32;
    if (idx >= total) return;
    int kk = idx & 31;
    int t  = idx >> 5;
    int co = t % CO;
    int s  = t / CO;
    float v = 0.0f;
    if (xmode && s == NSTEP - 1) {
        if (kk < 9) v = w[(co * CIT + 0) * 9 + kk];
    } else {
        int tap = s % 9;
        int cin = (s / 9) * 32 + kk + (xmode ? 1 : 0);
        v = w[(co * CIT + cin) * 9 + tap];
    }
    wf[idx] = f2h(v);
}

// ---- one GRU cell step for this WG's 8x32 tile ----
// L=0: h0' = cell(x_t, h0); L=1: h1' = cell(h0', h1). EMIT: write NCHW out
// instead of Hout (only for t=T-1, L=1).
template<int L, int EMIT>
__device__ __forceinline__ void do_cell(SmemT& sm,
    const unsigned short* __restrict__ Hin,
    unsigned short* __restrict__ Hout,
    const unsigned short* __restrict__ Xin,
    const float* __restrict__ seq, int t,
    const unsigned short* __restrict__ Wg, const float* __restrict__ bg,
    const unsigned short* __restrict__ Wc, const float* __restrict__ bc,
    float* __restrict__ out, int b, int R0, int C0)
{
    constexpr int KG = (L == 0) ? 10 : 18;
    constexpr int KC = (L == 0) ? 10 : 18;

    // ---- phase 0: staging (stage origin padded coords R0-1, C0-1) ----
    if (L == 0) {
        stage_plane12(sm.hs[0], Hin, b, R0 - 1, C0 - 1);
        if (threadIdx.x < 444) {
            int p = threadIdx.x;
            int r = p / 37, c = p - r * 37;
            int ir = R0 - 2 + r, ic = C0 - 2 + c;
            float v = 0.0f;
            if (ir >= 0 && ir < HH && ic >= 0 && ic < HH)
                v = seq[((long)b * TT + t) * HW + ir * HH + ic];
            sm.xt[p] = v;
        }
    } else {
        stage_plane12(sm.hs[0], Xin, b, R0 - 1, C0 - 1);
        stage_plane12(sm.hs[1], Hin, b, R0 - 1, C0 - 1);
    }
    __syncthreads();   // drains vmcnt(0): DMA complete

    const int wv = threadIdx.x >> 6, lane = threadIdx.x & 63;
    const int m16 = lane & 15, q = lane >> 4;
    const unsigned short* hp = (L == 0) ? sm.hs[0] : sm.hs[1];

    // ---- phase 1: gates conv on 10x34 (16 interior tiles aligned with the
    // cand fragment layout + 6 halo tiles on waves 2..7; halo = r-couts only)
    const bool HASH = (wv >= 2);
    int hgr = 0, hgc = 0;
    halo_rc10((wv - 2) * 16 + m16, hgr, hgc);

    f32x4 gI[2][4];
    f32x4 gH[2];
#pragma unroll
    for (int ng = 0; ng < 4; ++ng) {
        float bv = bg[ng * 16 + m16];
#pragma unroll
        for (int mg = 0; mg < 2; ++mg) gI[mg][ng] = f32x4{bv, bv, bv, bv};
        if (ng < 2) gH[ng] = f32x4{bv, bv, bv, bv};
    }

#pragma unroll
    for (int s = 0; s < KG; ++s) {
        f16x8 Bf[4];
#pragma unroll
        for (int ng = 0; ng < 4; ++ng)
            Bf[ng] = ld_frag(Wg + (s * 64 + ng * 16 + m16) * 32 + q * 8);
        f16x8 AI[2], AH;
        if (L == 0 && s == 9) {
#pragma unroll
            for (int mg = 0; mg < 2; ++mg)
                AI[mg] = x_im2col(sm.xt, wv + 1, mg * 16 + 1 + m16, q);
            AH = x_im2col(sm.xt, hgr, hgc, q);
        } else {
            const int tap = (L == 0) ? s : (s % 9);
            const unsigned short* pl = (L == 1 && s >= 9) ? sm.hs[1] : sm.hs[0];
#pragma unroll
            for (int mg = 0; mg < 2; ++mg)
                AI[mg] = lds_frag_w(pl, (wv + 1 + tap / 3) * 36 + mg * 16 + 1 + m16 + tap % 3, q);
            AH = lds_frag_w(pl, (hgr + tap / 3) * 36 + hgc + tap % 3, q);
        }
#pragma unroll
        for (int mg = 0; mg < 2; ++mg)
#pragma unroll
            for (int ng = 0; ng < 4; ++ng)
                gI[mg][ng] = __builtin_amdgcn_mfma_f32_16x16x32_f16(AI[mg], Bf[ng], gI[mg][ng], 0, 0, 0);
        if (HASH) {
#pragma unroll
            for (int ng = 0; ng < 2; ++ng)
                gH[ng] = __builtin_amdgcn_mfma_f32_16x16x32_f16(AH, Bf[ng], gH[ng], 0, 0, 0);
        }
    }

    // gates epilogue. C layout: col(n)=lane&15, row(pixel)=q*4+rg.
    // Interior: r*h -> rh LDS; z -> packed f16x2 regs (thread-aligned with
    // the update epilogue). Halo: r*h only.
    unsigned int zpk[2][4];
#pragma unroll
    for (int mg = 0; mg < 2; ++mg)
#pragma unroll
        for (int rg = 0; rg < 4; ++rg) {
            int gr = wv + 1, gc = mg * 16 + 1 + q * 4 + rg;
            zpk[mg][rg] = (unsigned int)f2h(sigmoid_f(gI[mg][2][rg]))
                        | ((unsigned int)f2h(sigmoid_f(gI[mg][3][rg])) << 16);
#pragma unroll
            for (int ng = 0; ng < 2; ++ng) {
                int n = ng * 16 + m16;
                float rv = sigmoid_f(gI[mg][ng][rg]);
                float hv = h2f(hp[((gr + 1) * 36 + gc + 1) * 32 + n]);
                sm.rh[(gr * 34 + gc) * 32 + n] = f2h(rv * hv);
            }
        }
    if (HASH) {
#pragma unroll
        for (int rg = 0; rg < 4; ++rg) {
            int gr, gc; halo_rc10((wv - 2) * 16 + q * 4 + rg, gr, gc);
#pragma unroll
            for (int ng = 0; ng < 2; ++ng) {
                int n = ng * 16 + m16;
                float rv = sigmoid_f(gH[ng][rg]);
                float hv = h2f(hp[((gr + 1) * 36 + gc + 1) * 32 + n]);
                sm.rh[(gr * 34 + gc) * 32 + n] = f2h(rv * hv);
            }
        }
    }
    __syncthreads();

    // ---- phase 2: candidate conv on interior 8x32 (wave = 1 row, 2 m-tiles)
    f32x4 cacc[2][2];
#pragma unroll
    for (int mg = 0; mg < 2; ++mg)
#pragma unroll
        for (int ng = 0; ng < 2; ++ng) {
            float bv = bc[ng * 16 + m16];
            cacc[mg][ng] = f32x4{bv, bv, bv, bv};
        }
#pragma unroll
    for (int s = 0; s < KC; ++s) {
        f16x8 Bf[2];
#pragma unroll
        for (int ng = 0; ng < 2; ++ng)
            Bf[ng] = ld_frag(Wc + (s * 32 + ng * 16 + m16) * 32 + q * 8);
        f16x8 A2[2];
        if (L == 0 && s == 9) {
#pragma unroll
            for (int mg = 0; mg < 2; ++mg)
                A2[mg] = x_im2col(sm.xt, wv + 1, mg * 16 + 1 + m16, q);
        } else if (L == 1 && s < 9) {
#pragma unroll
            for (int mg = 0; mg < 2; ++mg)
                A2[mg] = lds_frag_w(sm.hs[0], (wv + 1 + s / 3) * 36 + mg * 16 + m16 + 1 + s % 3, q);
        } else {
            const int tap = (L == 0) ? s : (s - 9);
#pragma unroll
            for (int mg = 0; mg < 2; ++mg)
                A2[mg] = lds_frag_w(sm.rh, (wv + tap / 3) * 34 + mg * 16 + m16 + tap % 3, q);
        }
#pragma unroll
        for (int mg = 0; mg < 2; ++mg)
#pragma unroll
            for (int ng = 0; ng < 2; ++ng)
                cacc[mg][ng] = __builtin_amdgcn_mfma_f32_16x16x32_f16(A2[mg], Bf[ng], cacc[mg][ng], 0, 0, 0);
    }

    // ---- update epilogue: h' = (1-z)*h_old + z*tanh(n) ----
    unsigned short hvout[2][2][4];
#pragma unroll
    for (int mg = 0; mg < 2; ++mg)
#pragma unroll
        for (int ng = 0; ng < 2; ++ng)
#pragma unroll
            for (int rg = 0; rg < 4; ++rg) {
                int lcol = mg * 16 + q * 4 + rg;
                int n = ng * 16 + m16;
                float nv = tanh_f(cacc[mg][ng][rg]);
                float zz = h2f((unsigned short)(zpk[mg][rg] >> (ng * 16)));
                float ho = h2f(hp[((wv + 2) * 36 + lcol + 2) * 32 + n]);
                float hnew = (1.0f - zz) * ho + zz * nv;
                if (!EMIT) {
                    long psp = (long)(b * PH + R0 + wv + 1) * PH + (C0 + lcol + 1);
                    Hout[psp * 32 + n] = f2h(hnew);
                } else {
                    hvout[mg][ng][rg] = f2h(hnew);
                }
            }

    if (EMIT) {
        // NCHW out via LDS transpose; rh is dead after cand -> scratch.
        __syncthreads();
        unsigned short* scr = sm.rh;      // [8 rows][32 cols][32 ch]
#pragma unroll
        for (int mg = 0; mg < 2; ++mg)
#pragma unroll
            for (int ng = 0; ng < 2; ++ng)
#pragma unroll
                for (int rg = 0; rg < 4; ++rg)
                    scr[((wv * 32 + mg * 16 + q * 4 + rg) * 32) + ng * 16 + m16] = hvout[mg][ng][rg];
        __syncthreads();
        const int tid = threadIdx.x;
        const int rowid = tid >> 1, half = tid & 1;
        const int n = rowid >> 3, wr = rowid & 7;
        long obase = ((long)(b * 32 + n) * HH + (R0 + wr)) * HH + C0 + half * 16;
#pragma unroll
        for (int j = 0; j < 16; ++j)
            out[obase + j] = h2f(scr[(wr * 32 + half * 16 + j) * 32 + n]);
    }
}

// ---- persistent cooperative kernel: whole T-loop, grid 512 x 512thr ----
__global__ __launch_bounds__(512, 4)
void gru_persistent(unsigned short* S0A, unsigned short* S0B,
                    unsigned short* S1A, unsigned short* S1B,
                    const float* seq,
                    const unsigned short* WG0, const float* gb0,
                    const unsigned short* WC0, const float* cb0,
                    const unsigned short* WG1, const float* gb1,
                    const unsigned short* WC1, const float* cb1,
                    float* out)
{
    __shared__ __align__(16) SmemT sm;
    cg::grid_group gg = cg::this_grid();
    const int wg = blockIdx.x;
    const int b = wg >> 6, tr = (wg >> 2) & 15, tc = wg & 3;
    const int R0 = tr * 8, C0 = tc * 32;
    unsigned short *h0r = S0A, *h0w = S0B, *h1r = S1A, *h1w = S1B;
    for (int t = 0; t < TT; ++t) {
        do_cell<0, 0>(sm, h0r, h0w, (const unsigned short*)0, seq, t,
                      WG0, gb0, WC0, cb0, (float*)0, b, R0, C0);
        gg.sync();
        if (t == TT - 1) {
            do_cell<1, 1>(sm, h1r, h1w, h0w, seq, t,
                          WG1, gb1, WC1, cb1, out, b, R0, C0);
        } else {
            do_cell<1, 0>(sm, h1r, h1w, h0w, seq, t,
                          WG1, gb1, WC1, cb1, (float*)0, b, R0, C0);
            gg.sync();
        }
        unsigned short* tmp;
        tmp = h0r; h0r = h0w; h0w = tmp;
        tmp = h1r; h1r = h1w; h1w = tmp;
    }
}

// ---- fallback: one (layer, t) per dispatch (kernel-boundary coherence) ----
template<int L, int EMIT>
__global__ __launch_bounds__(512, 4)
void gru_step(const unsigned short* __restrict__ Hin,
              unsigned short* __restrict__ Hout,
              const unsigned short* __restrict__ Xin,
              const float* __restrict__ seq, int t,
              const unsigned short* __restrict__ Wg, const float* __restrict__ bg,
              const unsigned short* __restrict__ Wc, const float* __restrict__ bc,
              float* __restrict__ out)
{
    __shared__ __align__(16) SmemT sm;
    const int wg = blockIdx.x;
    const int b = wg >> 6, tr = (wg >> 2) & 15, tc = wg & 3;
    do_cell<L, EMIT>(sm, Hin, Hout, Xin, seq, t, Wg, bg, Wc, bc, out,
                     b, tr * 8, tc * 32);
}

extern "C" void kernel_launch(void* const* d_in, const int* in_sizes, int n_in,
                              void* d_out, int out_size, void* d_ws, size_t ws_size,
                              hipStream_t stream)
{
    const float* seq = (const float*)d_in[0];
    const float* gw0 = (const float*)d_in[1];
    const float* gb0 = (const float*)d_in[2];
    const float* cw0 = (const float*)d_in[3];
    const float* cb0 = (const float*)d_in[4];
    const float* gw1 = (const float*)d_in[5];
    const float* gb1 = (const float*)d_in[6];
    const float* cw1 = (const float*)d_in[7];
    const float* cb1 = (const float*)d_in[8];
    float* out = (float*)d_out;

    const size_t NSP = (size_t)BB * PH * PH * 32;    // 4,326,400 fp16 per plane

    char* p = (char*)d_ws;
    unsigned short* S0A = (unsigned short*)p; p += NSP * 2;
    unsigned short* S0B = (unsigned short*)p; p += NSP * 2;
    unsigned short* S1A = (unsigned short*)p; p += NSP * 2;
    unsigned short* S1B = (unsigned short*)p; p += NSP * 2;
    unsigned short* WG0 = (unsigned short*)p; p += 20480 * 2;
    unsigned short* WC0 = (unsigned short*)p; p += 10240 * 2;
    unsigned short* WG1 = (unsigned short*)p; p += 36864 * 2;
    unsigned short* WC1 = (unsigned short*)p; p += 18432 * 2;

    // zero all 4 state planes (h=0 init + permanent zero halos), one span
    hipMemsetAsync(S0A, 0, 4 * NSP * 2, stream);

    prep_w<<<(10 * 64 * 32 + 255) / 256, 256, 0, stream>>>(gw0, WG0, 64, 33, 10, 1);
    prep_w<<<(10 * 32 * 32 + 255) / 256, 256, 0, stream>>>(cw0, WC0, 32, 33, 10, 1);
    prep_w<<<(18 * 64 * 32 + 255) / 256, 256, 0, stream>>>(gw1, WG1, 64, 64, 18, 0);
    prep_w<<<(18 * 32 * 32 + 255) / 256, 256, 0, stream>>>(cw1, WC1, 32, 64, 18, 0);

    void* ka[] = {
        (void*)&S0A, (void*)&S0B, (void*)&S1A, (void*)&S1B, (void*)&seq,
        (void*)&WG0, (void*)&gb0, (void*)&WC0, (void*)&cb0,
        (void*)&WG1, (void*)&gb1, (void*)&WC1, (void*)&cb1, (void*)&out
    };
    hipError_t e = hipLaunchCooperativeKernel((const void*)gru_persistent,
                                              dim3(512), dim3(512), ka, 0, stream);
    if (e != hipSuccess) {
        (void)hipGetLastError();   // clear error state; use per-step fallback
        unsigned short *h0r = S0A, *h0w = S0B, *h1r = S1A, *h1w = S1B;
        for (int t = 0; t < TT; ++t) {
            gru_step<0, 0><<<dim3(512), dim3(512), 0, stream>>>(
                h0r, h0w, (const unsigned short*)0, seq, t, WG0, gb0, WC0, cb0, (float*)0);
            if (t == TT - 1)
                gru_step<1, 1><<<dim3(512), dim3(512), 0, stream>>>(
                    h1r, h1w, h0w, seq, t, WG1, gb1, WC1, cb1, out);
            else
                gru_step<1, 0><<<dim3(512), dim3(512), 0, stream>>>(
                    h1r, h1w, h0w, seq, t, WG1, gb1, WC1, cb1, (float*)0);
            unsigned short* tmp;
            tmp = h0r; h0r = h0w; h0w = tmp;
            tmp = h1r; h1r = h1w; h1w = tmp;
        }
    }
}

// Round 5
// 1086.600 us; speedup vs baseline: 4.3478x; 4.3478x over previous
//
#include <hip/hip_runtime.h>

// ConvGRU, fp16 MFMA implicit GEMM.
// R4 post-mortem: persistent+grid.sync = 4.0GB FETCH (each grid.sync
// invalidates all per-XCD L2s; 47 syncs x ~150MB re-fetch) -> 4x SLOWER.
// Kernel boundaries are the cheaper coherence mechanism on this chip.
// R5: back to R3's verified cells, but MERGE independent steps:
//   L1(t) and L0(t+1) both depend only on h0'(t) and not on each other ->
//   one dispatch runs both (blockIdx.z selects role). Schedule:
//   [L0(0)], [L1(0)||L0(1)], ..., [L1(14)||L0(15)], [L1(15)+inline emit]
//   = 17 cell dispatches (was 32) + no final_out (NCHW emit via rh-scratch
//   transpose in the last L1; values bit-identical: h' passes through fp16
//   either way).
// States fp16 NHWC padded planes [B][130][130][32], 1-px zero halo,
// ping-pong buffered. Stage tile 8x36 (2-px halo) via global_load_lds;
// clamped rows/cols land in the zero halo ring == SAME-pad value.
// Tile 4 rows x 32 cols out per WG (4 waves), 128x8 tiles per role.

#define HH 128
#define PH 130
#define HW 16384
#define BB 8
#define TT 16

typedef _Float16 f16x8 __attribute__((ext_vector_type(8)));
typedef float f32x4 __attribute__((ext_vector_type(4)));
typedef unsigned int u32x4 __attribute__((ext_vector_type(4)));

__device__ __forceinline__ unsigned short f2h(float x){
    return __builtin_bit_cast(unsigned short, (_Float16)x);
}
__device__ __forceinline__ float h2f(unsigned short u){
    return (float)__builtin_bit_cast(_Float16, u);
}
__device__ __forceinline__ f16x8 ld_frag(const unsigned short* p){
    u32x4 v = *(const u32x4*)p;
    return __builtin_bit_cast(f16x8, v);
}
__device__ __forceinline__ f16x8 lds_frag_w(const unsigned short* base, int spix, int q){
    u32x4 v = *(const u32x4*)(base + spix * 32 + q * 8);
    return __builtin_bit_cast(f16x8, v);
}
__device__ __forceinline__ float sigmoid_f(float a){ return 1.0f / (1.0f + __expf(-a)); }
__device__ __forceinline__ float tanh_f(float a){ float e2 = __expf(2.0f * a); return 1.0f - 2.0f / (e2 + 1.0f); }

// halo enumeration for 6x34 gates region: 76 px (rows 0,5 full; rows 1-4
// cols 0,33) as 5 16-px M-tiles; s>75 clamps (benign same-value dups).
__device__ __forceinline__ void halo_rc(int s, int& gr, int& gc){
    s = s > 75 ? 75 : s;
    if (s < 34)      { gr = 0;            gc = s;      }
    else if (s < 68) { gr = 5;            gc = s - 34; }
    else if (s < 72) { gr = 1 + (s - 68); gc = 0;      }
    else             { gr = 1 + (s - 72); gc = 33;     }
}

// im2col x fragment for gates pixel (gr,gc) in 6x34 gates coords
__device__ __forceinline__ f16x8 x_im2col(const float* xt, int gr, int gc, int q){
    f16x8 v;
#pragma unroll
    for (int j = 0; j < 8; ++j) {
        int k = q * 8 + j;
        float f = 0.0f;
        if (k < 9) f = xt[(gr + k / 3) * 37 + gc + k % 3];
        v[j] = (_Float16)f;
    }
    return v;
}

// ---- async DMA staging: 8x36 pixel tile (288 px * 4 chunks = 18 wave-iters)
__device__ __forceinline__ void stage_plane(unsigned short* slot,
    const unsigned short* __restrict__ g, int b, int prow0, int pcol0)
{
    const int wv = threadIdx.x >> 6, lane = threadIdx.x & 63;
    for (int k = wv; k < 18; k += 4) {
        int chunk = k * 64 + lane;
        int pix = chunk >> 2, part = chunk & 3;
        int r = pix / 36, c = pix - r * 36;
        int pr = prow0 + r; pr = pr < 0 ? 0 : (pr > 129 ? 129 : pr);
        int pc = pcol0 + c; pc = pc < 0 ? 0 : (pc > 129 ? 129 : pc);
        const unsigned short* ga = g + ((long)((b * PH + pr) * PH + pc) * 32 + part * 8);
        __builtin_amdgcn_global_load_lds(
            (const __attribute__((address_space(1))) unsigned int*)ga,
            (__attribute__((address_space(3))) unsigned int*)(slot + k * 512),
            16, 0, 0);
    }
}

// ---- weight prep: [cout][cin_tot][9] fp32 -> [step][cout][32] fp16 ----
__global__ void prep_w(const float* __restrict__ w, unsigned short* __restrict__ wf,
                       int CO, int CIT, int NSTEP, int xmode)
{
    int idx = blockIdx.x * 256 + threadIdx.x;
    int total = NSTEP * CO * 32;
    if (idx >= total) return;
    int kk = idx & 31;
    int t  = idx >> 5;
    int co = t % CO;
    int s  = t / CO;
    float v = 0.0f;
    if (xmode && s == NSTEP - 1) {
        if (kk < 9) v = w[(co * CIT + 0) * 9 + kk];
    } else {
        int tap = s % 9;
        int cin = (s / 9) * 32 + kk + (xmode ? 1 : 0);
        v = w[(co * CIT + cin) * 9 + tap];
    }
    wf[idx] = f2h(v);
}

// ---- one GRU cell for a 4x32 tile. L=0: h0'=cell(x_t,h0); L=1: h1'=cell(h0',h1)
// EMIT (L=1 only): write NCHW fp32 out instead of Hout.
template<int L, int EMIT>
__device__ __forceinline__ void do_cell(
    unsigned short* hs0, unsigned short* hs1, unsigned short* rh, float* xt,
    const unsigned short* __restrict__ Hin,
    unsigned short* __restrict__ Hout,
    const unsigned short* __restrict__ Xin,
    const float* __restrict__ seq, int t,
    const unsigned short* __restrict__ Wg, const float* __restrict__ bg,
    const unsigned short* __restrict__ Wc, const float* __restrict__ bc,
    float* __restrict__ out, int b, int R0, int C0)
{
    constexpr int KG = (L == 0) ? 10 : 18;
    constexpr int KC = (L == 0) ? 10 : 18;
    const int prow0 = R0 - 1, pcol0 = C0 - 1;

    // ---- phase 0: staging ----
    if (L == 0) {
        stage_plane(hs0, Hin, b, prow0, pcol0);
        const float* x = seq + ((long)b * TT + t) * HW;
        for (int p = threadIdx.x; p < 288; p += 256) {
            int r = p / 36, c = p - r * 36;
            int ir = R0 - 2 + r, ic = C0 - 2 + c;
            float v = 0.0f;
            if (ir >= 0 && ir < HH && ic >= 0 && ic < HH) v = x[ir * HH + ic];
            xt[r * 37 + c] = v;
        }
    } else {
        stage_plane(hs0, Xin, b, prow0, pcol0);
        stage_plane(hs1, Hin, b, prow0, pcol0);
    }
    __syncthreads();   // drains vmcnt(0): DMA complete

    const int wv = threadIdx.x >> 6, lane = threadIdx.x & 63;
    const int m16 = lane & 15, q = lane >> 4;
    const unsigned short* hp = (L == 0) ? hs0 : hs1;   // old-h plane

    // ---- phase 1: gates conv on 6x34 (8 interior tiles aligned with cand
    // layout + 5 halo tiles; halo computes r-couts only) ----
    int hr0, hc0, hr1, hc1;
    halo_rc(wv * 16 + m16, hr0, hc0);
    halo_rc(64 + m16, hr1, hc1);
    const bool HAS2 = (wv == 0);

    f32x4 gI[2][4];
    f32x4 gH[2][2];
#pragma unroll
    for (int ng = 0; ng < 4; ++ng) {
        float bv = bg[ng * 16 + m16];
#pragma unroll
        for (int mg = 0; mg < 2; ++mg) gI[mg][ng] = f32x4{bv, bv, bv, bv};
        if (ng < 2) { gH[0][ng] = f32x4{bv, bv, bv, bv}; gH[1][ng] = f32x4{bv, bv, bv, bv}; }
    }

#pragma unroll
    for (int s = 0; s < KG; ++s) {
        f16x8 Bf[4];
#pragma unroll
        for (int ng = 0; ng < 4; ++ng)
            Bf[ng] = ld_frag(Wg + (s * 64 + ng * 16 + m16) * 32 + q * 8);
        f16x8 AI[2], AH0, AH1;
        if (L == 0 && s == 9) {
#pragma unroll
            for (int mg = 0; mg < 2; ++mg)
                AI[mg] = x_im2col(xt, wv + 1, mg * 16 + 1 + m16, q);
            AH0 = x_im2col(xt, hr0, hc0, q);
            if (HAS2) AH1 = x_im2col(xt, hr1, hc1, q);
        } else {
            const int tap = (L == 0) ? s : (s % 9);
            const unsigned short* pl = (L == 1 && s >= 9) ? hs1 : hs0;
#pragma unroll
            for (int mg = 0; mg < 2; ++mg)
                AI[mg] = lds_frag_w(pl, (wv + 1 + tap / 3) * 36 + mg * 16 + 1 + m16 + tap % 3, q);
            AH0 = lds_frag_w(pl, (hr0 + tap / 3) * 36 + hc0 + tap % 3, q);
            if (HAS2) AH1 = lds_frag_w(pl, (hr1 + tap / 3) * 36 + hc1 + tap % 3, q);
        }
#pragma unroll
        for (int mg = 0; mg < 2; ++mg)
#pragma unroll
            for (int ng = 0; ng < 4; ++ng)
                gI[mg][ng] = __builtin_amdgcn_mfma_f32_16x16x32_f16(AI[mg], Bf[ng], gI[mg][ng], 0, 0, 0);
#pragma unroll
        for (int ng = 0; ng < 2; ++ng)
            gH[0][ng] = __builtin_amdgcn_mfma_f32_16x16x32_f16(AH0, Bf[ng], gH[0][ng], 0, 0, 0);
        if (HAS2) {
#pragma unroll
            for (int ng = 0; ng < 2; ++ng)
                gH[1][ng] = __builtin_amdgcn_mfma_f32_16x16x32_f16(AH1, Bf[ng], gH[1][ng], 0, 0, 0);
        }
    }

    // gates epilogue. C layout: col(n)=lane&15, row(pixel)=q*4+rg.
    // Interior: r*h -> rh LDS; z -> packed f16x2 regs (thread-aligned with
    // update epilogue). Halo: r*h only.
    unsigned int zpk[2][4];
#pragma unroll
    for (int mg = 0; mg < 2; ++mg)
#pragma unroll
        for (int rg = 0; rg < 4; ++rg) {
            int gr = wv + 1, gc = mg * 16 + 1 + q * 4 + rg;
            zpk[mg][rg] = (unsigned int)f2h(sigmoid_f(gI[mg][2][rg]))
                        | ((unsigned int)f2h(sigmoid_f(gI[mg][3][rg])) << 16);
#pragma unroll
            for (int ng = 0; ng < 2; ++ng) {
                int n = ng * 16 + m16;
                float rv = sigmoid_f(gI[mg][ng][rg]);
                float hv = h2f(hp[((gr + 1) * 36 + gc + 1) * 32 + n]);
                rh[(gr * 34 + gc) * 32 + n] = f2h(rv * hv);
            }
        }
#pragma unroll
    for (int rg = 0; rg < 4; ++rg) {
        int gr, gc; halo_rc(wv * 16 + q * 4 + rg, gr, gc);
#pragma unroll
        for (int ng = 0; ng < 2; ++ng) {
            int n = ng * 16 + m16;
            float rv = sigmoid_f(gH[0][ng][rg]);
            float hv = h2f(hp[((gr + 1) * 36 + gc + 1) * 32 + n]);
            rh[(gr * 34 + gc) * 32 + n] = f2h(rv * hv);
        }
    }
    if (HAS2) {
#pragma unroll
        for (int rg = 0; rg < 4; ++rg) {
            int gr, gc; halo_rc(64 + q * 4 + rg, gr, gc);
#pragma unroll
            for (int ng = 0; ng < 2; ++ng) {
                int n = ng * 16 + m16;
                float rv = sigmoid_f(gH[1][ng][rg]);
                float hv = h2f(hp[((gr + 1) * 36 + gc + 1) * 32 + n]);
                rh[(gr * 34 + gc) * 32 + n] = f2h(rv * hv);
            }
        }
    }
    __syncthreads();

    // ---- phase 2: candidate conv on interior 4x32 (wave = 1 row, 2 m-tiles)
    f32x4 cacc[2][2];
#pragma unroll
    for (int mg = 0; mg < 2; ++mg)
#pragma unroll
        for (int ng = 0; ng < 2; ++ng) {
            float bv = bc[ng * 16 + m16];
            cacc[mg][ng] = f32x4{bv, bv, bv, bv};
        }
#pragma unroll
    for (int s = 0; s < KC; ++s) {
        f16x8 Bf[2];
#pragma unroll
        for (int ng = 0; ng < 2; ++ng)
            Bf[ng] = ld_frag(Wc + (s * 32 + ng * 16 + m16) * 32 + q * 8);
        f16x8 A2[2];
        if (L == 0 && s == 9) {
#pragma unroll
            for (int mg = 0; mg < 2; ++mg)
                A2[mg] = x_im2col(xt, wv + 1, mg * 16 + 1 + m16, q);
        } else if (L == 1 && s < 9) {
#pragma unroll
            for (int mg = 0; mg < 2; ++mg)
                A2[mg] = lds_frag_w(hs0, (wv + 1 + s / 3) * 36 + mg * 16 + m16 + 1 + s % 3, q);
        } else {
            const int tap = (L == 0) ? s : (s - 9);
#pragma unroll
            for (int mg = 0; mg < 2; ++mg)
                A2[mg] = lds_frag_w(rh, (wv + tap / 3) * 34 + mg * 16 + m16 + tap % 3, q);
        }
#pragma unroll
        for (int mg = 0; mg < 2; ++mg)
#pragma unroll
            for (int ng = 0; ng < 2; ++ng)
                cacc[mg][ng] = __builtin_amdgcn_mfma_f32_16x16x32_f16(A2[mg], Bf[ng], cacc[mg][ng], 0, 0, 0);
    }

    // ---- update epilogue: h' = (1-z)*h_old + z*tanh(n) ----
    unsigned short hvout[2][2][4];
#pragma unroll
    for (int mg = 0; mg < 2; ++mg)
#pragma unroll
        for (int ng = 0; ng < 2; ++ng)
#pragma unroll
            for (int rg = 0; rg < 4; ++rg) {
                int lcol = mg * 16 + q * 4 + rg;
                int n = ng * 16 + m16;
                float nv = tanh_f(cacc[mg][ng][rg]);
                float zz = h2f((unsigned short)(zpk[mg][rg] >> (ng * 16)));
                float ho = h2f(hp[((wv + 2) * 36 + lcol + 2) * 32 + n]);
                float hnew = (1.0f - zz) * ho + zz * nv;
                if (!EMIT) {
                    long psp = (long)(b * PH + R0 + wv + 1) * PH + (C0 + lcol + 1);
                    Hout[psp * 32 + n] = f2h(hnew);
                } else {
                    hvout[mg][ng][rg] = f2h(hnew);
                }
            }

    if (EMIT) {
        // NCHW fp32 out via LDS transpose; rh dead after cand -> scratch.
        // scr[4 rows][32 cols][32 ch] = 8192 ushorts <= rh's 6528*... (13,056B).
        __syncthreads();
        unsigned short* scr = rh;
#pragma unroll
        for (int mg = 0; mg < 2; ++mg)
#pragma unroll
            for (int ng = 0; ng < 2; ++ng)
#pragma unroll
                for (int rg = 0; rg < 4; ++rg)
                    scr[((wv * 32 + mg * 16 + q * 4 + rg) * 32) + ng * 16 + m16] = hvout[mg][ng][rg];
        __syncthreads();
        const int tid = threadIdx.x;
        const int rowid = tid >> 1, half = tid & 1;  // rowid: (c,wr) pair
        const int c = rowid >> 2, wr = rowid & 3;
        long obase = ((long)(b * 32 + c) * HH + (R0 + wr)) * HH + C0 + half * 16;
#pragma unroll
        for (int j = 0; j < 16; ++j)
            out[obase + j] = h2f(scr[(wr * 32 + half * 16 + j) * 32 + c]);
    }
}

// LDS footprints: L1/pair needs 2 planes; L0-solo needs 1 (4 WG/CU).
// sizes (B): hs plane 18,432 each; rh 13,056; xt 1,216.

// ---- solo L0 (t=0) ----
__global__ __launch_bounds__(256, 4)
void cell_l0(const unsigned short* __restrict__ Hin, unsigned short* __restrict__ Hout,
             const float* __restrict__ seq, int t,
             const unsigned short* __restrict__ Wg, const float* __restrict__ bg,
             const unsigned short* __restrict__ Wc, const float* __restrict__ bc)
{
    __shared__ __align__(16) unsigned short hs0[9216];
    __shared__ __align__(16) unsigned short rh[6528];
    __shared__ float xt[304];
    const int b = blockIdx.y, tc = blockIdx.x & 3, tr = blockIdx.x >> 2;
    do_cell<0, 0>(hs0, hs0, rh, xt, Hin, Hout, (const unsigned short*)0,
                  seq, t, Wg, bg, Wc, bc, (float*)0, b, tr * 4, tc * 32);
}

// ---- merged pair: z=0 -> L1(t), z=1 -> L0(t+1); both read h0r ----
__global__ __launch_bounds__(256, 3)
void step_pair(const unsigned short* __restrict__ h1r, unsigned short* __restrict__ h1w,
               const unsigned short* __restrict__ h0r, unsigned short* __restrict__ h0w,
               const float* __restrict__ seq, int tnext,
               const unsigned short* __restrict__ WG0, const float* __restrict__ gb0,
               const unsigned short* __restrict__ WC0, const float* __restrict__ cb0,
               const unsigned short* __restrict__ WG1, const float* __restrict__ gb1,
               const unsigned short* __restrict__ WC1, const float* __restrict__ cb1)
{
    __shared__ __align__(16) unsigned short hs[2][9216];
    __shared__ __align__(16) unsigned short rh[6528];
    __shared__ float xt[304];
    const int b = blockIdx.y, tc = blockIdx.x & 3, tr = blockIdx.x >> 2;
    if (blockIdx.z == 0)
        do_cell<1, 0>(hs[0], hs[1], rh, xt, h1r, h1w, h0r,
                      seq, 0, WG1, gb1, WC1, cb1, (float*)0, b, tr * 4, tc * 32);
    else
        do_cell<0, 0>(hs[0], hs[1], rh, xt, h0r, h0w, (const unsigned short*)0,
                      seq, tnext, WG0, gb0, WC0, cb0, (float*)0, b, tr * 4, tc * 32);
}

// ---- final L1(T-1) with inline NCHW emit ----
__global__ __launch_bounds__(256, 3)
void cell_l1_emit(const unsigned short* __restrict__ Hin,
                  const unsigned short* __restrict__ Xin,
                  const unsigned short* __restrict__ Wg, const float* __restrict__ bg,
                  const unsigned short* __restrict__ Wc, const float* __restrict__ bc,
                  float* __restrict__ out)
{
    __shared__ __align__(16) unsigned short hs[2][9216];
    __shared__ __align__(16) unsigned short rh[6528];
    __shared__ float xt[4];
    const int b = blockIdx.y, tc = blockIdx.x & 3, tr = blockIdx.x >> 2;
    do_cell<1, 1>(hs[0], hs[1], rh, xt, Hin, (unsigned short*)0, Xin,
                  (const float*)0, 0, Wg, bg, Wc, bc, out, b, tr * 4, tc * 32);
}

extern "C" void kernel_launch(void* const* d_in, const int* in_sizes, int n_in,
                              void* d_out, int out_size, void* d_ws, size_t ws_size,
                              hipStream_t stream)
{
    const float* seq = (const float*)d_in[0];
    const float* gw0 = (const float*)d_in[1];
    const float* gb0 = (const float*)d_in[2];
    const float* cw0 = (const float*)d_in[3];
    const float* cb0 = (const float*)d_in[4];
    const float* gw1 = (const float*)d_in[5];
    const float* gb1 = (const float*)d_in[6];
    const float* cw1 = (const float*)d_in[7];
    const float* cb1 = (const float*)d_in[8];
    float* out = (float*)d_out;

    const size_t NSP = (size_t)BB * PH * PH * 32;    // 4,326,400 fp16 per plane

    char* p = (char*)d_ws;
    unsigned short* S0A = (unsigned short*)p; p += NSP * 2;
    unsigned short* S0B = (unsigned short*)p; p += NSP * 2;
    unsigned short* S1A = (unsigned short*)p; p += NSP * 2;
    unsigned short* S1B = (unsigned short*)p; p += NSP * 2;
    unsigned short* WG0 = (unsigned short*)p; p += 20480 * 2;
    unsigned short* WC0 = (unsigned short*)p; p += 10240 * 2;
    unsigned short* WG1 = (unsigned short*)p; p += 36864 * 2;
    unsigned short* WC1 = (unsigned short*)p; p += 18432 * 2;

    // zero all 4 state planes (h=0 init + permanent zero halos), one span
    hipMemsetAsync(S0A, 0, 4 * NSP * 2, stream);

    prep_w<<<(10 * 64 * 32 + 255) / 256, 256, 0, stream>>>(gw0, WG0, 64, 33, 10, 1);
    prep_w<<<(10 * 32 * 32 + 255) / 256, 256, 0, stream>>>(cw0, WC0, 32, 33, 10, 1);
    prep_w<<<(18 * 64 * 32 + 255) / 256, 256, 0, stream>>>(gw1, WG1, 64, 64, 18, 0);
    prep_w<<<(18 * 32 * 32 + 255) / 256, 256, 0, stream>>>(cw1, WC1, 32, 64, 18, 0);

    dim3 grid1(128, BB, 1), grid2(128, BB, 2), block(256);

    // t=0, layer 0: reads S0A (zeros) writes S0B
    cell_l0<<<grid1, block, 0, stream>>>(S0A, S0B, seq, 0, WG0, gb0, WC0, cb0);

    // merged pairs: dispatch k runs L1(t=k) and L0(t=k+1)
    unsigned short *h0r = S0B, *h0w = S0A, *h1r = S1A, *h1w = S1B;
    for (int t = 0; t < TT - 1; ++t) {
        step_pair<<<grid2, block, 0, stream>>>(h1r, h1w, h0r, h0w, seq, t + 1,
                                               WG0, gb0, WC0, cb0,
                                               WG1, gb1, WC1, cb1);
        unsigned short* tmp;
        tmp = h0r; h0r = h0w; h0w = tmp;
        tmp = h1r; h1r = h1w; h1w = tmp;
    }
    // final: L1(15) reads h1r + h0r (h0'(15)), emits NCHW fp32 out
    cell_l1_emit<<<grid1, block, 0, stream>>>(h1r, h0r, WG1, gb1, WC1, cb1, out);
}

// Round 6
// 966.816 us; speedup vs baseline: 4.8864x; 1.1239x over previous
//
#include <hip/hip_runtime.h>

// ConvGRU, fp16 MFMA implicit GEMM.
// R6 = R5's 17-dispatch schedule (L0(0); 15x [L1(t)||L0(t+1)]; L1(15)+emit)
//      + R4's harness-verified 8x32-tile / 512-thread cell geometry
//      + register double-buffered weight-fragment prefetch.
// Why (R5 counters): step_pair MfmaUtil 11%, VALU 28%, Occ 28% -> latency-
// bound at 12 waves/CU. 512-thr cell gives 2 WG/CU x 8 waves = 16 waves/CU,
// better wave balance, fewer WG rounds; B-frag prefetch hides L2 latency.
// States fp16 NHWC padded planes [B][130][130][32], 1-px zero halo,
// ping-pong buffered. Stage tile 12x36 (2-px halo) via global_load_lds;
// clamped rows/cols land in the zero halo ring == SAME-pad value.

#define HH 128
#define PH 130
#define HW 16384
#define BB 8
#define TT 16

typedef _Float16 f16x8 __attribute__((ext_vector_type(8)));
typedef float f32x4 __attribute__((ext_vector_type(4)));
typedef unsigned int u32x4 __attribute__((ext_vector_type(4)));

__device__ __forceinline__ unsigned short f2h(float x){
    return __builtin_bit_cast(unsigned short, (_Float16)x);
}
__device__ __forceinline__ float h2f(unsigned short u){
    return (float)__builtin_bit_cast(_Float16, u);
}
__device__ __forceinline__ f16x8 ld_frag(const unsigned short* p){
    u32x4 v = *(const u32x4*)p;
    return __builtin_bit_cast(f16x8, v);
}
__device__ __forceinline__ f16x8 lds_frag_w(const unsigned short* base, int spix, int q){
    u32x4 v = *(const u32x4*)(base + spix * 32 + q * 8);
    return __builtin_bit_cast(f16x8, v);
}
__device__ __forceinline__ float sigmoid_f(float a){ return 1.0f / (1.0f + __expf(-a)); }
__device__ __forceinline__ float tanh_f(float a){ float e2 = __expf(2.0f * a); return 1.0f - 2.0f / (e2 + 1.0f); }

// LDS block: 2 stage planes 12x36x32 fp16 + rh 10x34x32 fp16 + x 12x37 fp32
struct SmemT {
    unsigned short hs[2][13824];   // 55,296 B
    unsigned short rh[10880];      // 21,760 B (also out-transpose scratch)
    float xt[444];                 //  1,776 B   => 78,832 B total
};

// halo enumeration for 10x34 gates region: 84 px (rows 0,9 full; rows 1..8
// cols 0,33) as 6 16-px M-tiles; s>83 clamps (benign same-value dups).
__device__ __forceinline__ void halo_rc10(int s, int& gr, int& gc){
    s = s > 83 ? 83 : s;
    if (s < 34)      { gr = 0;            gc = s;      }
    else if (s < 68) { gr = 9;            gc = s - 34; }
    else if (s < 76) { gr = 1 + (s - 68); gc = 0;      }
    else             { gr = 1 + (s - 76); gc = 33;     }
}

// im2col x fragment for gates pixel (gr,gc); xt stride 37, origin R0-2,C0-2
__device__ __forceinline__ f16x8 x_im2col(const float* xt, int gr, int gc, int q){
    f16x8 v;
#pragma unroll
    for (int j = 0; j < 8; ++j) {
        int k = q * 8 + j;
        float f = 0.0f;
        if (k < 9) f = xt[(gr + k / 3) * 37 + gc + k % 3];
        v[j] = (_Float16)f;
    }
    return v;
}

// ---- async DMA staging: 12x36 tile = 432 px * 4 chunks = 1728 = 27*64 ----
__device__ __forceinline__ void stage_plane12(unsigned short* slot,
    const unsigned short* __restrict__ g, int b, int pr0, int pc0)
{
    const int wv = threadIdx.x >> 6, lane = threadIdx.x & 63;
    for (int k = wv; k < 27; k += 8) {
        int chunk = k * 64 + lane;
        int pix = chunk >> 2, part = chunk & 3;
        int r = pix / 36, c = pix - r * 36;
        int pr = pr0 + r; pr = pr < 0 ? 0 : (pr > 129 ? 129 : pr);
        int pc = pc0 + c; pc = pc < 0 ? 0 : (pc > 129 ? 129 : pc);
        const unsigned short* ga = g + ((long)((b * PH + pr) * PH + pc) * 32 + part * 8);
        __builtin_amdgcn_global_load_lds(
            (const __attribute__((address_space(1))) unsigned int*)ga,
            (__attribute__((address_space(3))) unsigned int*)(slot + k * 512),
            16, 0, 0);
    }
}

// ---- weight prep: [cout][cin_tot][9] fp32 -> [step][cout][32] fp16 ----
__global__ void prep_w(const float* __restrict__ w, unsigned short* __restrict__ wf,
                       int CO, int CIT, int NSTEP, int xmode)
{
    int idx = blockIdx.x * 256 + threadIdx.x;
    int total = NSTEP * CO * 32;
    if (idx >= total) return;
    int kk = idx & 31;
    int t  = idx >> 5;
    int co = t % CO;
    int s  = t / CO;
    float v = 0.0f;
    if (xmode && s == NSTEP - 1) {
        if (kk < 9) v = w[(co * CIT + 0) * 9 + kk];
    } else {
        int tap = s % 9;
        int cin = (s / 9) * 32 + kk + (xmode ? 1 : 0);
        v = w[(co * CIT + cin) * 9 + tap];
    }
    wf[idx] = f2h(v);
}

// ---- one GRU cell step for this WG's 8x32 tile (R4-verified geometry) ----
// L=0: h0' = cell(x_t, h0); L=1: h1' = cell(h0', h1). EMIT: NCHW fp32 out.
template<int L, int EMIT>
__device__ __forceinline__ void do_cell(SmemT& sm,
    const unsigned short* __restrict__ Hin,
    unsigned short* __restrict__ Hout,
    const unsigned short* __restrict__ Xin,
    const float* __restrict__ seq, int t,
    const unsigned short* __restrict__ Wg, const float* __restrict__ bg,
    const unsigned short* __restrict__ Wc, const float* __restrict__ bc,
    float* __restrict__ out, int b, int R0, int C0)
{
    constexpr int KG = (L == 0) ? 10 : 18;
    constexpr int KC = (L == 0) ? 10 : 18;

    // ---- phase 0: staging (stage origin padded coords R0-1, C0-1) ----
    if (L == 0) {
        stage_plane12(sm.hs[0], Hin, b, R0 - 1, C0 - 1);
        if (threadIdx.x < 444) {
            int p = threadIdx.x;
            int r = p / 37, c = p - r * 37;
            int ir = R0 - 2 + r, ic = C0 - 2 + c;
            float v = 0.0f;
            if (ir >= 0 && ir < HH && ic >= 0 && ic < HH)
                v = seq[((long)b * TT + t) * HW + ir * HH + ic];
            sm.xt[p] = v;
        }
    } else {
        stage_plane12(sm.hs[0], Xin, b, R0 - 1, C0 - 1);
        stage_plane12(sm.hs[1], Hin, b, R0 - 1, C0 - 1);
    }
    __syncthreads();   // drains vmcnt(0): DMA complete

    const int wv = threadIdx.x >> 6, lane = threadIdx.x & 63;
    const int m16 = lane & 15, q = lane >> 4;
    const unsigned short* hp = (L == 0) ? sm.hs[0] : sm.hs[1];

    // ---- phase 1: gates conv on 10x34 (16 interior tiles aligned with the
    // cand fragment layout + 6 halo tiles on waves 2..7; halo = r-couts only)
    const bool HASH = (wv >= 2);
    int hgr = 0, hgc = 0;
    halo_rc10((wv - 2) * 16 + m16, hgr, hgc);

    f32x4 gI[2][4];
    f32x4 gH[2];
#pragma unroll
    for (int ng = 0; ng < 4; ++ng) {
        float bv = bg[ng * 16 + m16];
#pragma unroll
        for (int mg = 0; mg < 2; ++mg) gI[mg][ng] = f32x4{bv, bv, bv, bv};
        if (ng < 2) gH[ng] = f32x4{bv, bv, bv, bv};
    }

    // register double-buffered B-fragments: load s+1 before MFMA(s)
    f16x8 Bc[4];
#pragma unroll
    for (int ng = 0; ng < 4; ++ng)
        Bc[ng] = ld_frag(Wg + (ng * 16 + m16) * 32 + q * 8);

#pragma unroll
    for (int s = 0; s < KG; ++s) {
        f16x8 Bn[4];
        if (s + 1 < KG) {
#pragma unroll
            for (int ng = 0; ng < 4; ++ng)
                Bn[ng] = ld_frag(Wg + ((s + 1) * 64 + ng * 16 + m16) * 32 + q * 8);
        }
        f16x8 AI[2], AH;
        if (L == 0 && s == 9) {
#pragma unroll
            for (int mg = 0; mg < 2; ++mg)
                AI[mg] = x_im2col(sm.xt, wv + 1, mg * 16 + 1 + m16, q);
            AH = x_im2col(sm.xt, hgr, hgc, q);
        } else {
            const int tap = (L == 0) ? s : (s % 9);
            const unsigned short* pl = (L == 1 && s >= 9) ? sm.hs[1] : sm.hs[0];
#pragma unroll
            for (int mg = 0; mg < 2; ++mg)
                AI[mg] = lds_frag_w(pl, (wv + 1 + tap / 3) * 36 + mg * 16 + 1 + m16 + tap % 3, q);
            AH = lds_frag_w(pl, (hgr + tap / 3) * 36 + hgc + tap % 3, q);
        }
#pragma unroll
        for (int mg = 0; mg < 2; ++mg)
#pragma unroll
            for (int ng = 0; ng < 4; ++ng)
                gI[mg][ng] = __builtin_amdgcn_mfma_f32_16x16x32_f16(AI[mg], Bc[ng], gI[mg][ng], 0, 0, 0);
        if (HASH) {
#pragma unroll
            for (int ng = 0; ng < 2; ++ng)
                gH[ng] = __builtin_amdgcn_mfma_f32_16x16x32_f16(AH, Bc[ng], gH[ng], 0, 0, 0);
        }
        if (s + 1 < KG) {
#pragma unroll
            for (int ng = 0; ng < 4; ++ng) Bc[ng] = Bn[ng];
        }
    }

    // gates epilogue. C layout: col(n)=lane&15, row(pixel)=q*4+rg.
    // Interior: r*h -> rh LDS; z -> packed f16x2 regs (thread-aligned with
    // the update epilogue). Halo: r*h only.
    unsigned int zpk[2][4];
#pragma unroll
    for (int mg = 0; mg < 2; ++mg)
#pragma unroll
        for (int rg = 0; rg < 4; ++rg) {
            int gr = wv + 1, gc = mg * 16 + 1 + q * 4 + rg;
            zpk[mg][rg] = (unsigned int)f2h(sigmoid_f(gI[mg][2][rg]))
                        | ((unsigned int)f2h(sigmoid_f(gI[mg][3][rg])) << 16);
#pragma unroll
            for (int ng = 0; ng < 2; ++ng) {
                int n = ng * 16 + m16;
                float rv = sigmoid_f(gI[mg][ng][rg]);
                float hv = h2f(hp[((gr + 1) * 36 + gc + 1) * 32 + n]);
                sm.rh[(gr * 34 + gc) * 32 + n] = f2h(rv * hv);
            }
        }
    if (HASH) {
#pragma unroll
        for (int rg = 0; rg < 4; ++rg) {
            int gr, gc; halo_rc10((wv - 2) * 16 + q * 4 + rg, gr, gc);
#pragma unroll
            for (int ng = 0; ng < 2; ++ng) {
                int n = ng * 16 + m16;
                float rv = sigmoid_f(gH[ng][rg]);
                float hv = h2f(hp[((gr + 1) * 36 + gc + 1) * 32 + n]);
                sm.rh[(gr * 34 + gc) * 32 + n] = f2h(rv * hv);
            }
        }
    }
    __syncthreads();

    // ---- phase 2: candidate conv on interior 8x32 (wave = 1 row, 2 m-tiles)
    f32x4 cacc[2][2];
#pragma unroll
    for (int mg = 0; mg < 2; ++mg)
#pragma unroll
        for (int ng = 0; ng < 2; ++ng) {
            float bv = bc[ng * 16 + m16];
            cacc[mg][ng] = f32x4{bv, bv, bv, bv};
        }
    f16x8 Cc[2];
#pragma unroll
    for (int ng = 0; ng < 2; ++ng)
        Cc[ng] = ld_frag(Wc + (ng * 16 + m16) * 32 + q * 8);
#pragma unroll
    for (int s = 0; s < KC; ++s) {
        f16x8 Cn[2];
        if (s + 1 < KC) {
#pragma unroll
            for (int ng = 0; ng < 2; ++ng)
                Cn[ng] = ld_frag(Wc + ((s + 1) * 32 + ng * 16 + m16) * 32 + q * 8);
        }
        f16x8 A2[2];
        if (L == 0 && s == 9) {
#pragma unroll
            for (int mg = 0; mg < 2; ++mg)
                A2[mg] = x_im2col(sm.xt, wv + 1, mg * 16 + 1 + m16, q);
        } else if (L == 1 && s < 9) {
#pragma unroll
            for (int mg = 0; mg < 2; ++mg)
                A2[mg] = lds_frag_w(sm.hs[0], (wv + 1 + s / 3) * 36 + mg * 16 + m16 + 1 + s % 3, q);
        } else {
            const int tap = (L == 0) ? s : (s - 9);
#pragma unroll
            for (int mg = 0; mg < 2; ++mg)
                A2[mg] = lds_frag_w(sm.rh, (wv + tap / 3) * 34 + mg * 16 + m16 + tap % 3, q);
        }
#pragma unroll
        for (int mg = 0; mg < 2; ++mg)
#pragma unroll
            for (int ng = 0; ng < 2; ++ng)
                cacc[mg][ng] = __builtin_amdgcn_mfma_f32_16x16x32_f16(A2[mg], Cc[ng], cacc[mg][ng], 0, 0, 0);
        if (s + 1 < KC) {
#pragma unroll
            for (int ng = 0; ng < 2; ++ng) Cc[ng] = Cn[ng];
        }
    }

    // ---- update epilogue: h' = (1-z)*h_old + z*tanh(n) ----
    unsigned short hvout[2][2][4];
#pragma unroll
    for (int mg = 0; mg < 2; ++mg)
#pragma unroll
        for (int ng = 0; ng < 2; ++ng)
#pragma unroll
            for (int rg = 0; rg < 4; ++rg) {
                int lcol = mg * 16 + q * 4 + rg;
                int n = ng * 16 + m16;
                float nv = tanh_f(cacc[mg][ng][rg]);
                float zz = h2f((unsigned short)(zpk[mg][rg] >> (ng * 16)));
                float ho = h2f(hp[((wv + 2) * 36 + lcol + 2) * 32 + n]);
                float hnew = (1.0f - zz) * ho + zz * nv;
                if (!EMIT) {
                    long psp = (long)(b * PH + R0 + wv + 1) * PH + (C0 + lcol + 1);
                    Hout[psp * 32 + n] = f2h(hnew);
                } else {
                    hvout[mg][ng][rg] = f2h(hnew);
                }
            }

    if (EMIT) {
        // NCHW out via LDS transpose; rh is dead after cand -> scratch.
        __syncthreads();
        unsigned short* scr = sm.rh;      // [8 rows][32 cols][32 ch]
#pragma unroll
        for (int mg = 0; mg < 2; ++mg)
#pragma unroll
            for (int ng = 0; ng < 2; ++ng)
#pragma unroll
                for (int rg = 0; rg < 4; ++rg)
                    scr[((wv * 32 + mg * 16 + q * 4 + rg) * 32) + ng * 16 + m16] = hvout[mg][ng][rg];
        __syncthreads();
        const int tid = threadIdx.x;
        const int rowid = tid >> 1, half = tid & 1;
        const int n = rowid >> 3, wr = rowid & 7;
        long obase = ((long)(b * 32 + n) * HH + (R0 + wr)) * HH + C0 + half * 16;
#pragma unroll
        for (int j = 0; j < 16; ++j)
            out[obase + j] = h2f(scr[(wr * 32 + half * 16 + j) * 32 + n]);
    }
}

// ---- solo L0 (t=0): 512 WGs ----
__global__ __launch_bounds__(512, 4)
void cell_l0(const unsigned short* __restrict__ Hin, unsigned short* __restrict__ Hout,
             const float* __restrict__ seq, int t,
             const unsigned short* __restrict__ Wg, const float* __restrict__ bg,
             const unsigned short* __restrict__ Wc, const float* __restrict__ bc)
{
    __shared__ __align__(16) SmemT sm;
    const int wg = blockIdx.x;
    const int b = wg >> 6, tr = (wg >> 2) & 15, tc = wg & 3;
    do_cell<0, 0>(sm, Hin, Hout, (const unsigned short*)0, seq, t,
                  Wg, bg, Wc, bc, (float*)0, b, tr * 8, tc * 32);
}

// ---- merged pair: z=0 -> L1(t), z=1 -> L0(t+1); both read h0r ----
__global__ __launch_bounds__(512, 4)
void step_pair(const unsigned short* __restrict__ h1r, unsigned short* __restrict__ h1w,
               const unsigned short* __restrict__ h0r, unsigned short* __restrict__ h0w,
               const float* __restrict__ seq, int tnext,
               const unsigned short* __restrict__ WG0, const float* __restrict__ gb0,
               const unsigned short* __restrict__ WC0, const float* __restrict__ cb0,
               const unsigned short* __restrict__ WG1, const float* __restrict__ gb1,
               const unsigned short* __restrict__ WC1, const float* __restrict__ cb1)
{
    __shared__ __align__(16) SmemT sm;
    const int wg = blockIdx.x;
    const int b = wg >> 6, tr = (wg >> 2) & 15, tc = wg & 3;
    if (blockIdx.z == 0)
        do_cell<1, 0>(sm, h1r, h1w, h0r, seq, 0,
                      WG1, gb1, WC1, cb1, (float*)0, b, tr * 8, tc * 32);
    else
        do_cell<0, 0>(sm, h0r, h0w, (const unsigned short*)0, seq, tnext,
                      WG0, gb0, WC0, cb0, (float*)0, b, tr * 8, tc * 32);
}

// ---- final L1(T-1) with inline NCHW emit ----
__global__ __launch_bounds__(512, 4)
void cell_l1_emit(const unsigned short* __restrict__ Hin,
                  const unsigned short* __restrict__ Xin,
                  const unsigned short* __restrict__ Wg, const float* __restrict__ bg,
                  const unsigned short* __restrict__ Wc, const float* __restrict__ bc,
                  float* __restrict__ out)
{
    __shared__ __align__(16) SmemT sm;
    const int wg = blockIdx.x;
    const int b = wg >> 6, tr = (wg >> 2) & 15, tc = wg & 3;
    do_cell<1, 1>(sm, Hin, (unsigned short*)0, Xin, (const float*)0, 0,
                  Wg, bg, Wc, bc, out, b, tr * 8, tc * 32);
}

extern "C" void kernel_launch(void* const* d_in, const int* in_sizes, int n_in,
                              void* d_out, int out_size, void* d_ws, size_t ws_size,
                              hipStream_t stream)
{
    const float* seq = (const float*)d_in[0];
    const float* gw0 = (const float*)d_in[1];
    const float* gb0 = (const float*)d_in[2];
    const float* cw0 = (const float*)d_in[3];
    const float* cb0 = (const float*)d_in[4];
    const float* gw1 = (const float*)d_in[5];
    const float* gb1 = (const float*)d_in[6];
    const float* cw1 = (const float*)d_in[7];
    const float* cb1 = (const float*)d_in[8];
    float* out = (float*)d_out;

    const size_t NSP = (size_t)BB * PH * PH * 32;    // 4,326,400 fp16 per plane

    char* p = (char*)d_ws;
    unsigned short* S0A = (unsigned short*)p; p += NSP * 2;
    unsigned short* S0B = (unsigned short*)p; p += NSP * 2;
    unsigned short* S1A = (unsigned short*)p; p += NSP * 2;
    unsigned short* S1B = (unsigned short*)p; p += NSP * 2;
    unsigned short* WG0 = (unsigned short*)p; p += 20480 * 2;
    unsigned short* WC0 = (unsigned short*)p; p += 10240 * 2;
    unsigned short* WG1 = (unsigned short*)p; p += 36864 * 2;
    unsigned short* WC1 = (unsigned short*)p; p += 18432 * 2;

    // zero all 4 state planes (h=0 init + permanent zero halos), one span
    hipMemsetAsync(S0A, 0, 4 * NSP * 2, stream);

    prep_w<<<(10 * 64 * 32 + 255) / 256, 256, 0, stream>>>(gw0, WG0, 64, 33, 10, 1);
    prep_w<<<(10 * 32 * 32 + 255) / 256, 256, 0, stream>>>(cw0, WC0, 32, 33, 10, 1);
    prep_w<<<(18 * 64 * 32 + 255) / 256, 256, 0, stream>>>(gw1, WG1, 64, 64, 18, 0);
    prep_w<<<(18 * 32 * 32 + 255) / 256, 256, 0, stream>>>(cw1, WC1, 32, 64, 18, 0);

    dim3 grid1(512, 1, 1), grid2(512, 1, 2), block(512);

    // t=0, layer 0: reads S0A (zeros) writes S0B
    cell_l0<<<grid1, block, 0, stream>>>(S0A, S0B, seq, 0, WG0, gb0, WC0, cb0);

    // merged pairs: dispatch k runs L1(t=k) and L0(t=k+1)
    unsigned short *h0r = S0B, *h0w = S0A, *h1r = S1A, *h1w = S1B;
    for (int t = 0; t < TT - 1; ++t) {
        step_pair<<<grid2, block, 0, stream>>>(h1r, h1w, h0r, h0w, seq, t + 1,
                                               WG0, gb0, WC0, cb0,
                                               WG1, gb1, WC1, cb1);
        unsigned short* tmp;
        tmp = h0r; h0r = h0w; h0w = tmp;
        tmp = h1r; h1r = h1w; h1w = tmp;
    }
    // final: L1(15) reads h1r + h0r (h0'(15)), emits NCHW fp32 out
    cell_l1_emit<<<grid1, block, 0, stream>>>(h1r, h0r, WG1, gb1, WC1, cb1, out);
}